// Round 3
// baseline (153.172 us; speedup 1.0000x reference)
//
#include <hip/hip_runtime.h>
#include <math.h>

constexpr int N_LOC     = 100000;
constexpr int D_IN      = 128;
constexpr int N_ROUTES  = 8192;
constexpr int ROUTE_LEN = 100;
constexpr int D_OUT     = 256;
constexpr float LN_EPS  = 1e-5f;

constexpr int RPB      = 4;    // routes per block -> 2048 blocks = 8 blocks/CU
constexpr int NTHREADS = 256;
constexpr int PSTRIDE  = 132;  // padded pooled row stride (floats): banks offset 4 per route

__global__ __launch_bounds__(NTHREADS, 8)   // 8 waves/SIMD, caps VGPR at 64
void routes_encoder_kernel(const float* __restrict__ emb,    // [N_LOC, D_IN]
                           const int*   __restrict__ idx,    // [N_ROUTES, ROUTE_LEN]
                           const float* __restrict__ W,      // [D_IN, D_OUT]
                           const float* __restrict__ bias,   // [D_OUT]
                           const float* __restrict__ gamma,  // [D_OUT]
                           const float* __restrict__ beta,   // [D_OUT]
                           float* __restrict__ out)          // [N_ROUTES, D_OUT]
{
    __shared__ int   s_idx[RPB * ROUTE_LEN];      // 1600 B
    __shared__ float s_pooled[RPB][PSTRIDE];      // 2112 B
    __shared__ float s_sum[4][RPB];
    __shared__ float s_ssq[4][RPB];

    const int tid    = threadIdx.x;
    const int route0 = blockIdx.x * RPB;

    // ---- 1. stage indices (coalesced) ----
    for (int i = tid; i < RPB * ROUTE_LEN; i += NTHREADS)
        s_idx[i] = idx[(size_t)route0 * ROUTE_LEN + i];
    __syncthreads();

    // ---- 2. gather + max-pool: wave w owns route w; 2 locations per wave-load ----
    {
        const int w    = tid >> 6;        // wave = route
        const int lane = tid & 63;
        const int half = lane >> 5;       // 0: even t, 1: odd t
        const int d4   = (lane & 31) * 4; // dim offset (float4 slot)
        const int* gi  = &s_idx[w * ROUTE_LEN];
        float4 m = make_float4(-INFINITY, -INFINITY, -INFINITY, -INFINITY);
        #pragma unroll 10
        for (int t = 0; t < ROUTE_LEN / 2; ++t) {
            const int row = gi[2 * t + half];
            const float4 v = *reinterpret_cast<const float4*>(
                emb + (size_t)row * D_IN + d4);
            m.x = fmaxf(m.x, v.x);
            m.y = fmaxf(m.y, v.y);
            m.z = fmaxf(m.z, v.z);
            m.w = fmaxf(m.w, v.w);
        }
        // combine even/odd halves: lane l <- max(lane l, lane l+32)
        m.x = fmaxf(m.x, __shfl_down(m.x, 32));
        m.y = fmaxf(m.y, __shfl_down(m.y, 32));
        m.z = fmaxf(m.z, __shfl_down(m.z, 32));
        m.w = fmaxf(m.w, __shfl_down(m.w, 32));
        if (lane < 32)
            *reinterpret_cast<float4*>(&s_pooled[w][d4]) = m;
    }
    __syncthreads();

    // ---- 3. GEMM + bias: thread = (route r, col-quad c4) ----
    const int r  = tid & 3;
    const int c4 = tid >> 2;           // cols 4*c4 .. 4*c4+3
    const float* Wp = W + 4 * c4;

    float4 h = *reinterpret_cast<const float4*>(bias + 4 * c4);
    #pragma unroll 8
    for (int k4 = 0; k4 < D_IN / 4; ++k4) {
        const float4 p = *reinterpret_cast<const float4*>(&s_pooled[r][k4 * 4]);
        const float pj[4] = {p.x, p.y, p.z, p.w};
        #pragma unroll
        for (int j = 0; j < 4; ++j) {
            const float4 wv = *reinterpret_cast<const float4*>(
                Wp + (size_t)(k4 * 4 + j) * D_OUT);
            h.x = fmaf(pj[j], wv.x, h.x);
            h.y = fmaf(pj[j], wv.y, h.y);
            h.z = fmaf(pj[j], wv.z, h.z);
            h.w = fmaf(pj[j], wv.w, h.w);
        }
    }

    // ---- 4. LayerNorm (E[x^2]-mu^2) + ReLU ----
    float s  = h.x + h.y + h.z + h.w;
    float ss = h.x * h.x + h.y * h.y + h.z * h.z + h.w * h.w;
    #pragma unroll
    for (int off = 4; off < 64; off <<= 1) {
        s  += __shfl_xor(s,  off);
        ss += __shfl_xor(ss, off);
    }
    const int wave = tid >> 6;
    const int lane = tid & 63;
    if (lane < 4) { s_sum[wave][lane] = s; s_ssq[wave][lane] = ss; }  // lane==r here
    __syncthreads();

    const float tot = s_sum[0][r] + s_sum[1][r] + s_sum[2][r] + s_sum[3][r];
    const float tsq = s_ssq[0][r] + s_ssq[1][r] + s_ssq[2][r] + s_ssq[3][r];
    const float mu  = tot * (1.0f / D_OUT);
    const float var = tsq * (1.0f / D_OUT) - mu * mu;
    const float inv = rsqrtf(var + LN_EPS);

    const float4 gm = *reinterpret_cast<const float4*>(gamma + 4 * c4);
    const float4 bt = *reinterpret_cast<const float4*>(beta  + 4 * c4);
    float4 y;
    y.x = fmaxf((h.x - mu) * inv * gm.x + bt.x, 0.0f);
    y.y = fmaxf((h.y - mu) * inv * gm.y + bt.y, 0.0f);
    y.z = fmaxf((h.z - mu) * inv * gm.z + bt.z, 0.0f);
    y.w = fmaxf((h.w - mu) * inv * gm.w + bt.w, 0.0f);

    float* op = out + (size_t)(route0 + r) * D_OUT + 4 * c4;
    __builtin_nontemporal_store(y.x, op + 0);
    __builtin_nontemporal_store(y.y, op + 1);
    __builtin_nontemporal_store(y.z, op + 2);
    __builtin_nontemporal_store(y.w, op + 3);
}

extern "C" void kernel_launch(void* const* d_in, const int* in_sizes, int n_in,
                              void* d_out, int out_size, void* d_ws, size_t ws_size,
                              hipStream_t stream) {
    const float* emb   = (const float*)d_in[0];
    const int*   idx   = (const int*)  d_in[1];
    const float* W     = (const float*)d_in[2];
    const float* bias  = (const float*)d_in[3];
    const float* gamma = (const float*)d_in[4];
    const float* beta  = (const float*)d_in[5];
    float* out = (float*)d_out;

    routes_encoder_kernel<<<dim3(N_ROUTES / RPB), dim3(NTHREADS), 0, stream>>>(
        emb, idx, W, bias, gamma, beta, out);
}

// Round 8
// 139.889 us; speedup vs baseline: 1.0950x; 1.0950x over previous
//
#include <hip/hip_runtime.h>
#include <math.h>

constexpr int N_LOC     = 100000;
constexpr int D_IN      = 128;
constexpr int N_ROUTES  = 8192;
constexpr int ROUTE_LEN = 100;
constexpr int D_OUT     = 256;
constexpr float LN_EPS  = 1e-5f;

constexpr int RPB      = 4;    // routes per block -> 2048 blocks = 8 blocks/CU
constexpr int NTHREADS = 256;
constexpr size_t EMB_ELEMS = (size_t)N_LOC * D_IN;              // 12.8e6
constexpr size_t F16_BYTES = EMB_ELEMS * 2;                     // 25.6 MB

typedef __fp16 f16x2 __attribute__((ext_vector_type(2)));       // matches cvt_pkrtz return

__device__ inline unsigned pk_max_f16(unsigned a, unsigned b) {
    unsigned d;
    asm("v_pk_max_f16 %0, %1, %2" : "=v"(d) : "v"(a), "v"(b));
    return d;
}

// ---- pass 1: fp32 table -> packed-fp16 table in d_ws (streams ~77 MB) ----
__global__ __launch_bounds__(256, 8)
void convert_f16_kernel(const float* __restrict__ emb, unsigned* __restrict__ emb16) {
    size_t i = ((size_t)blockIdx.x * blockDim.x + threadIdx.x) * 4;   // elems
    const size_t stride = (size_t)gridDim.x * blockDim.x * 4;
    for (; i < EMB_ELEMS; i += stride) {
        const float4 v = *reinterpret_cast<const float4*>(emb + i);
        const f16x2 a = __builtin_amdgcn_cvt_pkrtz(v.x, v.y);
        const f16x2 b = __builtin_amdgcn_cvt_pkrtz(v.z, v.w);
        uint2 u;
        u.x = __builtin_bit_cast(unsigned, a);
        u.y = __builtin_bit_cast(unsigned, b);
        *reinterpret_cast<uint2*>(emb16 + i / 2) = u;
    }
}

// ---- pass 2: gather + maxpool + GEMM + LN + ReLU ----
template<bool F16>
__global__ __launch_bounds__(NTHREADS, 8)
void routes_encoder_kernel(const float*    __restrict__ emb,    // [N_LOC, D_IN] fp32
                           const unsigned* __restrict__ emb16,  // packed f16 (if F16)
                           const int*      __restrict__ idx,    // [N_ROUTES, ROUTE_LEN]
                           const float*    __restrict__ W,      // [D_IN, D_OUT]
                           const float*    __restrict__ bias,   // [D_OUT]
                           const float*    __restrict__ gamma,  // [D_OUT]
                           const float*    __restrict__ beta,   // [D_OUT]
                           float*          __restrict__ out)    // [N_ROUTES, D_OUT]
{
    __shared__ int   s_idx[RPB * ROUTE_LEN];
    __shared__ float s_pooled[RPB][D_IN];
    __shared__ float s_sum[4][RPB];
    __shared__ float s_ssq[4][RPB];

    const int tid    = threadIdx.x;
    const int route0 = blockIdx.x * RPB;

    // ---- stage indices (coalesced) ----
    for (int i = tid; i < RPB * ROUTE_LEN; i += NTHREADS)
        s_idx[i] = idx[(size_t)route0 * ROUTE_LEN + i];
    __syncthreads();

    const int w    = tid >> 6;    // wave = route
    const int lane = tid & 63;

    if constexpr (F16) {
        // 4 rows per wave-load: lane reads 16 B (8 halves) of row gi[4t + quarter]
        const int q  = lane >> 4;        // quarter 0..3
        const int dc = (lane & 15) * 8;  // dim chunk base (halves)
        const int* gi = &s_idx[w * ROUTE_LEN];
        unsigned m0 = 0xFC00FC00u, m1 = m0, m2 = m0, m3 = m0;  // packed -inf
        #pragma unroll 5
        for (int t = 0; t < ROUTE_LEN / 4; ++t) {
            const int row = gi[4 * t + q];
            const uint4 v = *reinterpret_cast<const uint4*>(
                emb16 + ((size_t)row * D_IN + dc) / 2);
            m0 = pk_max_f16(m0, v.x);
            m1 = pk_max_f16(m1, v.y);
            m2 = pk_max_f16(m2, v.z);
            m3 = pk_max_f16(m3, v.w);
        }
        // combine the 4 quarters: lane l <- max over l, l+16, l+32, l+48
        #pragma unroll
        for (int off = 32; off >= 16; off >>= 1) {
            m0 = pk_max_f16(m0, (unsigned)__shfl_down((int)m0, off));
            m1 = pk_max_f16(m1, (unsigned)__shfl_down((int)m1, off));
            m2 = pk_max_f16(m2, (unsigned)__shfl_down((int)m2, off));
            m3 = pk_max_f16(m3, (unsigned)__shfl_down((int)m3, off));
        }
        if (lane < 16) {
            const f16x2 h0 = __builtin_bit_cast(f16x2, m0);
            const f16x2 h1 = __builtin_bit_cast(f16x2, m1);
            const f16x2 h2 = __builtin_bit_cast(f16x2, m2);
            const f16x2 h3 = __builtin_bit_cast(f16x2, m3);
            *reinterpret_cast<float4*>(&s_pooled[w][dc]) =
                make_float4((float)h0.x, (float)h0.y, (float)h1.x, (float)h1.y);
            *reinterpret_cast<float4*>(&s_pooled[w][dc + 4]) =
                make_float4((float)h2.x, (float)h2.y, (float)h3.x, (float)h3.y);
        }
    } else {
        // proven R2 path: one row per wave-load, lane owns a float2 slice
        const int* gi = &s_idx[w * ROUTE_LEN];
        float2 m = make_float2(-INFINITY, -INFINITY);
        #pragma unroll 10
        for (int l = 0; l < ROUTE_LEN; ++l) {
            const float2 v = *reinterpret_cast<const float2*>(
                emb + (size_t)gi[l] * D_IN + lane * 2);
            m.x = fmaxf(m.x, v.x);
            m.y = fmaxf(m.y, v.y);
        }
        *reinterpret_cast<float2*>(&s_pooled[w][lane * 2]) = m;
    }
    __syncthreads();

    // ---- GEMM + bias (R2 mapping: thread = output column; W read once per block) ----
    float h[RPB];
    {
        const float bo = bias[tid];
        #pragma unroll
        for (int r = 0; r < RPB; ++r) h[r] = bo;

        #pragma unroll 8
        for (int k = 0; k < D_IN; k += 4) {
            const float wk0 = W[(size_t)(k + 0) * D_OUT + tid];
            const float wk1 = W[(size_t)(k + 1) * D_OUT + tid];
            const float wk2 = W[(size_t)(k + 2) * D_OUT + tid];
            const float wk3 = W[(size_t)(k + 3) * D_OUT + tid];
            #pragma unroll
            for (int r = 0; r < RPB; ++r) {
                const float4 p = *reinterpret_cast<const float4*>(&s_pooled[r][k]);
                h[r] = fmaf(p.x, wk0, h[r]);
                h[r] = fmaf(p.y, wk1, h[r]);
                h[r] = fmaf(p.z, wk2, h[r]);
                h[r] = fmaf(p.w, wk3, h[r]);
            }
        }
    }

    // ---- LayerNorm (E[x^2]-mu^2) + ReLU ----
    float s[RPB], ss[RPB];
    #pragma unroll
    for (int r = 0; r < RPB; ++r) { s[r] = h[r]; ss[r] = h[r] * h[r]; }

    #pragma unroll
    for (int off = 32; off > 0; off >>= 1) {
        #pragma unroll
        for (int r = 0; r < RPB; ++r) {
            s[r]  += __shfl_down(s[r],  off);
            ss[r] += __shfl_down(ss[r], off);
        }
    }
    if (lane == 0) {
        #pragma unroll
        for (int r = 0; r < RPB; ++r) { s_sum[w][r] = s[r]; s_ssq[w][r] = ss[r]; }
    }
    __syncthreads();

    const float gm = gamma[tid];
    const float bt = beta[tid];
    #pragma unroll
    for (int r = 0; r < RPB; ++r) {
        const float tot = s_sum[0][r] + s_sum[1][r] + s_sum[2][r] + s_sum[3][r];
        const float tsq = s_ssq[0][r] + s_ssq[1][r] + s_ssq[2][r] + s_ssq[3][r];
        const float mu  = tot * (1.0f / D_OUT);
        const float var = tsq * (1.0f / D_OUT) - mu * mu;
        const float inv = rsqrtf(var + LN_EPS);
        const float y   = fmaxf((h[r] - mu) * inv * gm + bt, 0.0f);
        __builtin_nontemporal_store(y, &out[(size_t)(route0 + r) * D_OUT + tid]);
    }
}

extern "C" void kernel_launch(void* const* d_in, const int* in_sizes, int n_in,
                              void* d_out, int out_size, void* d_ws, size_t ws_size,
                              hipStream_t stream) {
    const float* emb   = (const float*)d_in[0];
    const int*   idx   = (const int*)  d_in[1];
    const float* W     = (const float*)d_in[2];
    const float* bias  = (const float*)d_in[3];
    const float* gamma = (const float*)d_in[4];
    const float* beta  = (const float*)d_in[5];
    float* out = (float*)d_out;

    if (ws_size >= F16_BYTES) {
        unsigned* emb16 = (unsigned*)d_ws;
        convert_f16_kernel<<<dim3(2048), dim3(256), 0, stream>>>(emb, emb16);
        routes_encoder_kernel<true><<<dim3(N_ROUTES / RPB), dim3(NTHREADS), 0, stream>>>(
            emb, emb16, idx, W, bias, gamma, beta, out);
    } else {
        routes_encoder_kernel<false><<<dim3(N_ROUTES / RPB), dim3(NTHREADS), 0, stream>>>(
            emb, nullptr, idx, W, bias, gamma, beta, out);
    }
}